// Round 3
// baseline (120.058 us; speedup 1.0000x reference)
//
#include <hip/hip_runtime.h>

#define NIMG 4
#define NCLS 19
#define CCH  32
#define LH   128
#define LW   128
#define HH   512
#define WW   512
#define HWQ  (LH*LW)    // 16384
#define HWP  (HH*WW)    // 262144

#define TR 8
#define TC 16
#define NTILE 128       // field-role blocks per image (16x8 tiles)
#define TCELLS 128
#define HALO_R 36
#define HALO_C 68
#define QROWS 128       // quad-role blocks per image (one low-res row each)

// LDS layout (floats) for field role; quad role reuses first NCLS floats.
#define L_ET  0                     // Etile [cell*33 + c], 128*33 = 4224
#define L_A   4224                  // A [cell*19 + L],     128*19 = 2432
#define L_RED 6656                  // red [wave][608],     4*608  = 2432
#define LDS_FLOATS 9088             // 36.3 KB

// Bilinear taps, jax.image.resize half-pixel convention (128 -> 512).
// in = (v+0.5)/4 - 0.5 ; edge renormalization == clamping (verified absmax 0.0)
__device__ __forceinline__ void taps(int v, int lim, int& i0, int& i1, float& f) {
    int r = v & 3;
    int b = (v >> 2) + ((r < 2) ? -1 : 0);
    f = 0.125f + 0.25f * (float)((r + 2) & 3);
    i0 = b < 0 ? 0 : b;
    i1 = (b + 1 > lim) ? lim : (b + 1);
}

__global__ __launch_bounds__(256) void k_main(const float* __restrict__ E,
        const int* __restrict__ lab, float* __restrict__ P_sum,
        float* __restrict__ P_cnt, float* __restrict__ P_S2) {
    __shared__ float lds[LDS_FLOATS];
    const int n = blockIdx.y;
    const int tid = threadIdx.x;

    if (blockIdx.x < NTILE) {
        // ---------------- field role: LDS A-field + fused contract ----------
        const int tile = blockIdx.x;
        const int ty = tile >> 3, tx = tile & 7;
        const int Y0 = ty * TR, X0 = tx * TC;

        for (int i = tid; i < TCELLS * NCLS; i += 256) lds[L_A + i] = 0.f;
        // stage E tile: [cell][c] stride 33 (conflict-free write & read)
#pragma unroll
        for (int it = 0; it < 16; it++) {
            int idx = it * 256 + tid;             // [0,4096)
            int c = idx >> 7, cell = idx & 127;
            int cy = cell >> 4, cx = cell & 15;
            float e = E[((size_t)n * CCH + c) * HWQ + (Y0 + cy) * LW + (X0 + cx)];
            lds[L_ET + cell * 33 + c] = e;
        }
        __syncthreads();

        // halo gather: keep taps landing in owned region (LDS atomics only)
        const int* ln = lab + (size_t)n * HWP;
        int h_lo = Y0 * 4 - 2, w_lo = X0 * 4 - 2;
        for (int i = tid; i < HALO_R * HALO_C; i += 256) {
            int hr = i / HALO_C, wc = i - hr * HALO_C;
            int h = h_lo + hr, w = w_lo + wc;
            if (h < 0 || h >= HH || w < 0 || w >= WW) continue;
            int L = ln[h * WW + w];
            int y0, y1, x0, x1; float fy, fx;
            taps(h, LH - 1, y0, y1, fy);
            taps(w, LW - 1, x0, x1, fx);
            int yy[2] = {y0, y1}; float wy[2] = {1.f - fy, fy};
            int xx[2] = {x0, x1}; float wx[2] = {1.f - fx, fx};
#pragma unroll
            for (int a = 0; a < 2; a++) {
#pragma unroll
                for (int b = 0; b < 2; b++) {
                    int ry = yy[a] - Y0, rx = xx[b] - X0;
                    if (ry >= 0 && ry < TR && rx >= 0 && rx < TC)
                        atomicAdd(&lds[L_A + (ry * TC + rx) * NCLS + L], wy[a] * wx[b]);
                }
            }
        }
        __syncthreads();

        // contract: thread (g,c); E from LDS (lane-consecutive), A broadcast
        const int g = tid >> 5, c = tid & 31;
        float acc[NCLS];
#pragma unroll
        for (int k = 0; k < NCLS; k++) acc[k] = 0.f;
#pragma unroll
        for (int j = 0; j < 16; j++) {
            int cell = g * 16 + j;
            float e = lds[L_ET + cell * 33 + c];
            const float* Ar = &lds[L_A + cell * NCLS];
#pragma unroll
            for (int k = 0; k < NCLS; k++) acc[k] = fmaf(Ar[k], e, acc[k]);
        }
#pragma unroll
        for (int k = 0; k < NCLS; k++) acc[k] += __shfl_xor(acc[k], 32);
        const int wave = tid >> 6;
        if ((tid & 63) < 32) {
#pragma unroll
            for (int k = 0; k < NCLS; k++)
                lds[L_RED + wave * 608 + k * 32 + c] = acc[k];
        }
        __syncthreads();

        float* Ps = P_sum + (size_t)(n * NTILE + tile) * (NCLS * CCH);
        for (int i = tid; i < NCLS * CCH; i += 256) {
            float s = lds[L_RED + i] + lds[L_RED + 608 + i]
                    + lds[L_RED + 1216 + i] + lds[L_RED + 1824 + i];
            Ps[i] = s;
        }
        if (tid < NCLS) {
            float s = 0.f;
            for (int cell = 0; cell < TCELLS; cell++) s += lds[L_A + cell * NCLS + tid];
            P_cnt[((size_t)n * NCLS + tid) * NTILE + tile] = s;   // transposed
        }
    } else {
        // ---------------- quad role: S2[k] partial for one quad-row --------
        const int by = blockIdx.x - NTILE;       // 0..127
        const int half = tid >> 7, bx = tid & 127;
        if (tid < NCLS) lds[tid] = 0.f;
        __syncthreads();

        const float* En = E + ((size_t)n * CCH + half * 16) * HWQ;
        int r0 = (by == 0) ? 0 : by - 1;
        int r2 = (by == LH - 1) ? LH - 1 : by + 1;
        int c0 = (bx == 0) ? 0 : bx - 1;
        int c2 = (bx == LW - 1) ? LW - 1 : bx + 1;
        int o0 = r0 * LW, o1 = by * LW, o2 = r2 * LW;

        float d2[16];
#pragma unroll
        for (int i = 0; i < 16; i++) d2[i] = 0.f;

#pragma unroll
        for (int c = 0; c < 16; c++) {
            const float* Ep = En + (size_t)c * HWQ;
            float e00 = Ep[o0 + c0], e01 = Ep[o0 + bx], e02 = Ep[o0 + c2];
            float e10 = Ep[o1 + c0], e11 = Ep[o1 + bx], e12 = Ep[o1 + c2];
            float e20 = Ep[o2 + c0], e21 = Ep[o2 + bx], e22 = Ep[o2 + c2];
            float dy0 = e10 - e00, dy1 = e11 - e01, dy2 = e12 - e02;
            float dz0 = e20 - e10, dz1 = e21 - e11, dz2 = e22 - e12;
            float ry[4][3];
            ry[0][0] = fmaf(0.625f, dy0, e00); ry[0][1] = fmaf(0.625f, dy1, e01); ry[0][2] = fmaf(0.625f, dy2, e02);
            ry[1][0] = fmaf(0.875f, dy0, e00); ry[1][1] = fmaf(0.875f, dy1, e01); ry[1][2] = fmaf(0.875f, dy2, e02);
            ry[2][0] = fmaf(0.125f, dz0, e10); ry[2][1] = fmaf(0.125f, dz1, e11); ry[2][2] = fmaf(0.125f, dz2, e12);
            ry[3][0] = fmaf(0.375f, dz0, e10); ry[3][1] = fmaf(0.375f, dz1, e11); ry[3][2] = fmaf(0.375f, dz2, e12);
#pragma unroll
            for (int r = 0; r < 4; r++) {
                float da = ry[r][1] - ry[r][0], db = ry[r][2] - ry[r][1];
                float v0 = fmaf(0.625f, da, ry[r][0]);
                float v1 = fmaf(0.875f, da, ry[r][0]);
                float v2 = fmaf(0.125f, db, ry[r][1]);
                float v3 = fmaf(0.375f, db, ry[r][1]);
                d2[r * 4 + 0] = fmaf(v0, v0, d2[r * 4 + 0]);
                d2[r * 4 + 1] = fmaf(v1, v1, d2[r * 4 + 1]);
                d2[r * 4 + 2] = fmaf(v2, v2, d2[r * 4 + 2]);
                d2[r * 4 + 3] = fmaf(v3, v3, d2[r * 4 + 3]);
            }
        }
        const int* lp = lab + (size_t)n * HWP + (by * 4) * WW + bx * 4;
#pragma unroll
        for (int r = 0; r < 4; r++) {
            int4 l4 = *(const int4*)(lp + r * WW);
            atomicAdd(&lds[l4.x], d2[r * 4 + 0]);
            atomicAdd(&lds[l4.y], d2[r * 4 + 1]);
            atomicAdd(&lds[l4.z], d2[r * 4 + 2]);
            atomicAdd(&lds[l4.w], d2[r * 4 + 3]);
        }
        __syncthreads();
        if (tid < NCLS)
            P_S2[((size_t)n * NCLS + tid) * QROWS + by] = lds[tid];   // transposed
    }
}

// reduce partials; intra = (S2 - 2 m.s + cnt|m|^2)/32/(cnt+1); inter pairwise
__global__ __launch_bounds__(640) void k_final(const float* __restrict__ P_sum,
        const float* __restrict__ P_cnt, const float* __restrict__ P_S2,
        float* __restrict__ out) {
    const int n = blockIdx.x, t = threadIdx.x;
    __shared__ float csum[NCLS * 33];
    __shared__ float m[NCLS * 33];
    __shared__ float cnt[NCLS];
    __shared__ float S2[NCLS];
    __shared__ float sIntra, sNfg, sInter;
    if (t == 0) sInter = 0.f;

    if (t < NCLS * CCH) {
        const int k = t >> 5, c = t & 31;
        const float* p = P_sum + (size_t)n * NTILE * (NCLS * CCH) + t;
        float s = 0.f;
        for (int b = 0; b < NTILE; b++) s += p[b * (NCLS * CCH)];
        csum[k * 33 + c] = s;
        const float* pc = P_cnt + ((size_t)n * NCLS + k) * NTILE;
        float sc = pc[c] + pc[c + 32] + pc[c + 64] + pc[c + 96];
        const float* ps = P_S2 + ((size_t)n * NCLS + k) * QROWS;
        float s2 = ps[c] + ps[c + 32] + ps[c + 64] + ps[c + 96];
#pragma unroll
        for (int mk = 16; mk >= 1; mk >>= 1) {
            sc += __shfl_xor(sc, mk);
            s2 += __shfl_xor(s2, mk);
        }
        if (c == 0) { cnt[k] = sc; S2[k] = s2; }
    }
    __syncthreads();
    if (t < NCLS * CCH) {
        const int k = t >> 5, c = t & 31;
        m[k * 33 + c] = csum[k * 33 + c] / (cnt[k] + 1.f);
    }
    __syncthreads();

    // intra + n_fg (threads 1..18 live in wave 0)
    float vi = 0.f, fg = 0.f;
    if (t >= 1 && t < NCLS && cnt[t] > 0.f) {
        fg = 1.f;
        float dot = 0.f, mm = 0.f;
#pragma unroll
        for (int c = 0; c < CCH; c++) {
            float mv = m[t * 33 + c];
            dot = fmaf(mv, csum[t * 33 + c], dot);
            mm = fmaf(mv, mv, mm);
        }
        vi = (S2[t] - 2.f * dot + cnt[t] * mm) * (1.f / 32.f) / (cnt[t] + 1.f);
    }
#pragma unroll
    for (int s_ = 32; s_ >= 1; s_ >>= 1) { vi += __shfl_xor(vi, s_); fg += __shfl_xor(fg, s_); }
    if (t == 0) { sIntra = vi; sNfg = fg; }

    // inter: 18x18 foreground pairs
    float ve = 0.f;
    if (t < 324) {
        int j = 1 + t / 18, k = 1 + t % 18;
        if (cnt[j] > 0.f && cnt[k] > 0.f) {
            float s = 0.f;
#pragma unroll
            for (int c = 0; c < CCH; c++) {
                float d = m[j * 33 + c] - m[k * 33 + c];
                s = fmaf(d, d, s);
            }
            ve = s * (1.f / 32.f);
        }
    }
#pragma unroll
    for (int s_ = 32; s_ >= 1; s_ >>= 1) ve += __shfl_xor(ve, s_);
    if ((t & 63) == 0) atomicAdd(&sInter, ve);
    __syncthreads();
    if (t == 0) out[n] = sIntra / sNfg - sInter / (sNfg * sNfg);
}

extern "C" void kernel_launch(void* const* d_in, const int* in_sizes, int n_in,
                              void* d_out, int out_size, void* d_ws, size_t ws_size,
                              hipStream_t stream) {
    const float* E = (const float*)d_in[0];   // (4,32,128,128) fp32
    const int* lab = (const int*)d_in[1];     // (4,512,512) int
    float* out = (float*)d_out;               // (4,) fp32

    float* ws = (float*)d_ws;
    float* P_sum = ws;                                          // 4*128*608
    float* P_cnt = P_sum + (size_t)NIMG * NTILE * NCLS * CCH;   // 4*19*128
    float* P_S2  = P_cnt + (size_t)NIMG * NCLS * NTILE;         // 4*19*128
    // every partial slot fully overwritten each call -> no memset

    k_main <<<dim3(NTILE + QROWS, NIMG), dim3(256), 0, stream>>>(E, lab, P_sum, P_cnt, P_S2);
    k_final<<<dim3(NIMG), dim3(640), 0, stream>>>(P_sum, P_cnt, P_S2, out);
}